// Round 6
// baseline (43.675 us; speedup 1.0000x reference)
//
#include <hip/hip_runtime.h>

// YOLO loss: out,label [32768,17,7,7] f32 -> scalar f32.
// Fixed-phase flat float4 streaming. Group = 4 batches = 3332 floats = 833
// float4 exactly. Thread tid of a block owns float4 slots q = tid+256*s
// (s=0..2, +s=3 iff tid<65) in EVERY group -> its element offsets within a
// group are launch-invariant. Per-element metadata precomputed once into
// registers:  weights (a,bw) packed as 2x bf16 (exact for .5/5/1),
// mask offset moff = bat*833 + cell (within group), sqrt flag in bit31.
//   contrib = (a + bw*m) * d2,  m = lab[group_base + moff]  (L1/L2-hot;
//   for c==0 it's the element itself), d2 = (l-o)^2 or l+o-2*sqrt(l*o).
// Main loop: 13 coalesced dwordx4 loads issued up front per group (deep MLP),
// 13 hot mask dwords, ~12 VALU/element. No LDS, no divs, no barriers.
// Sum / (32768*49). Two-kernel deterministic reduction.

#define BPC          833
#define CELLS        49
#define GROUP_FLOATS 3332          // 4 batches
#define GROUP_F4     833           // float4 per tensor per group
#define NGROUPS      8192          // 32768 batches / 4
#define NBLK         2048
#define GPB          (NGROUPS / NBLK)   // 4 groups per block

__global__ __launch_bounds__(256) void yolo_partial(const float* __restrict__ outp,
                                                    const float* __restrict__ lab,
                                                    float* __restrict__ partial) {
    const int tid = threadIdx.x;

    // ---- launch-invariant per-thread metadata (registers; static indexing) ----
    unsigned metaW[4][4];   // (bf16 a)<<16 | (bf16 bw)
    unsigned metaM[4][4];   // moff | sqrt?<<31
#pragma unroll
    for (int s = 0; s < 4; ++s) {
#pragma unroll
        for (int j = 0; j < 4; ++j) {
            int E = 4 * (tid + 256 * s) + j;
            if (E >= GROUP_FLOATS) E = 0;            // slot unused (guarded below)
            const int bat  = E / BPC;
            const int rr   = E - bat * BPC;
            const int c    = rr / CELLS;
            const int cell = rr - c * CELLS;
            unsigned w;
            if (c == 0)      w = (0x3F00u << 16) | 0x3F00u;  // a=.5 bw=.5
            else if (c <= 4) w = 0x40A0u;                    // a=0  bw=5
            else             w = 0x3F80u;                    // a=0  bw=1
            metaW[s][j] = w;
            metaM[s][j] = (unsigned)(bat * BPC + cell)
                        | ((c == 3 || c == 4) ? 0x80000000u : 0u);
        }
    }

    const float4* __restrict__ o4p = (const float4*)outp;
    const float4* __restrict__ l4p = (const float4*)lab;
    const bool has3 = (tid < 65);

    float acc = 0.0f;
    for (int k = 0; k < GPB; ++k) {
        const int g   = blockIdx.x + k * NBLK;
        const int gf4 = g * GROUP_F4;
        const float* __restrict__ mbase = lab + g * GROUP_FLOATS;

        float4 ob[4], lb[4];
#pragma unroll
        for (int s = 0; s < 3; ++s) {                // issue all wide loads first
            ob[s] = o4p[gf4 + tid + 256 * s];
            lb[s] = l4p[gf4 + tid + 256 * s];
        }
        if (has3) {
            ob[3] = o4p[gf4 + tid + 768];
            lb[3] = l4p[gf4 + tid + 768];
        }

#pragma unroll
        for (int s = 0; s < 4; ++s) {
            if (s == 3 && !has3) break;
            const float ov[4] = {ob[s].x, ob[s].y, ob[s].z, ob[s].w};
            const float lv[4] = {lb[s].x, lb[s].y, lb[s].z, lb[s].w};
#pragma unroll
            for (int j = 0; j < 4; ++j) {
                const unsigned w  = metaW[s][j];
                const unsigned mm = metaM[s][j];
                const float a  = __uint_as_float(w & 0xFFFF0000u);
                const float bw = __uint_as_float(w << 16);
                const float m  = mbase[mm & 0x7FFFFFFFu];     // L1/L2-hot
                const float l1 = lv[j], o1 = ov[j];
                const float dl  = l1 - o1;
                const float dl2 = dl * dl;
                const float q2  = (l1 + o1) - 2.0f * __builtin_amdgcn_sqrtf(l1 * o1);
                const float d2  = ((int)mm < 0) ? q2 : dl2;
                acc = fmaf(fmaf(bw, m, a), d2, acc);
            }
        }
    }

    // wave64 shuffle reduce
#pragma unroll
    for (int off = 32; off > 0; off >>= 1)
        acc += __shfl_down(acc, off, 64);

    __shared__ float wsum[4];
    const int lane = threadIdx.x & 63;
    const int wid  = threadIdx.x >> 6;
    if (lane == 0) wsum[wid] = acc;
    __syncthreads();
    if (threadIdx.x == 0)
        partial[blockIdx.x] = wsum[0] + wsum[1] + wsum[2] + wsum[3];
}

__global__ __launch_bounds__(256) void yolo_final(const float* __restrict__ partial,
                                                  float* __restrict__ outv) {
    float acc = 0.0f;
    for (int i = threadIdx.x; i < NBLK; i += 256) acc += partial[i];
#pragma unroll
    for (int off = 32; off > 0; off >>= 1)
        acc += __shfl_down(acc, off, 64);

    __shared__ float wsum[4];
    const int lane = threadIdx.x & 63;
    const int wid  = threadIdx.x >> 6;
    if (lane == 0) wsum[wid] = acc;
    __syncthreads();
    if (threadIdx.x == 0)
        outv[0] = (wsum[0] + wsum[1] + wsum[2] + wsum[3]) * (1.0f / 1605632.0f);
}

extern "C" void kernel_launch(void* const* d_in, const int* in_sizes, int n_in,
                              void* d_out, int out_size, void* d_ws, size_t ws_size,
                              hipStream_t stream) {
    const float* outp = (const float*)d_in[0];
    const float* lab  = (const float*)d_in[1];
    float* partial    = (float*)d_ws;          // NBLK floats (8 KB)
    float* res        = (float*)d_out;

    yolo_partial<<<NBLK, 256, 0, stream>>>(outp, lab, partial);
    yolo_final<<<1, 256, 0, stream>>>(partial, res);
}